// Round 4
// baseline (461.997 us; speedup 1.0000x reference)
//
#include <hip/hip_runtime.h>
#include <math.h>

// DynamicConv on MI355X — round 4: occupancy-first restructure.
// conv block = 256o x 64px (one h-row), LDS 31.7KB -> 4-5 blocks/CU resident
// (was 42.5KB/~2 blocks, MfmaUtil 30%). + setprio around MFMA, ks-outer MFMA
// order (dep distance 4), BN-stats fused into conv epilogue (drops 64MB pass).
// Split bf16 hi/lo, 3 MFMA passes. MFMA floor ~93us.

#define B_ 16
#define C_ 256
#define O_ 256
#define HW_ 4096          // 64*64
#define PLANE_F4 1024
#define WPERK 589824      // O_*C_*9
#define XS_PX 40          // bf16 slots per pixel in LDS (32 ch + 8 pad)

typedef short bf16x8 __attribute__((ext_vector_type(8)));
typedef float f32x16 __attribute__((ext_vector_type(16)));

__device__ __forceinline__ unsigned short f2bf(float f) {
    unsigned u = __float_as_uint(f);
    u += 0x7FFFu + ((u >> 16) & 1u);
    return (unsigned short)(u >> 16);
}
__device__ __forceinline__ float bf2f(unsigned short h) {
    return __uint_as_float((unsigned)h << 16);
}

// ---------------- pool ----------------
__global__ __launch_bounds__(256) void pool_kernel(const float4* __restrict__ x4,
                                                   float* __restrict__ pooled) {
    int bc = blockIdx.x;
    const float4* p = x4 + (size_t)bc * PLANE_F4;
    float s = 0.f;
    for (int i = threadIdx.x; i < PLANE_F4; i += 256) {
        float4 v = p[i];
        s += v.x + v.y + v.z + v.w;
    }
    for (int off = 32; off; off >>= 1) s += __shfl_down(s, off);
    __shared__ float partial[4];
    if ((threadIdx.x & 63) == 0) partial[threadIdx.x >> 6] = s;
    __syncthreads();
    if (threadIdx.x == 0)
        pooled[bc] = (partial[0] + partial[1] + partial[2] + partial[3]) * (1.f / 4096.f);
}

// ---------------- attn ----------------
__global__ void attn_kernel(const float* __restrict__ pooled,
                            const float* __restrict__ attn_w,
                            float* __restrict__ attn) {
    int tid = threadIdx.x;                     // 64 threads
    int b = tid >> 2, k = tid & 3;
    float s = 0.f;
    for (int c = 0; c < C_; ++c) s += pooled[b * C_ + c] * attn_w[k * C_ + c];
    __shared__ float lg[16][4];
    lg[b][k] = s;
    __syncthreads();
    float m = fmaxf(fmaxf(lg[b][0], lg[b][1]), fmaxf(lg[b][2], lg[b][3]));
    float den = expf(lg[b][0] - m) + expf(lg[b][1] - m) +
                expf(lg[b][2] - m) + expf(lg[b][3] - m);
    attn[tid] = expf(s - m) / den;
}

// ---------------- wtrans: combine, split hi/lo, transpose to [b][o][t][c] ----------------
__global__ __launch_bounds__(256) void wtrans_kernel(const float* __restrict__ dyn,
                                                     const float* __restrict__ attn,
                                                     unsigned short* __restrict__ wt_hi,
                                                     unsigned short* __restrict__ wt_lo) {
    int idx = blockIdx.x * 256 + threadIdx.x;   // (b,o,c)
    int b = idx >> 16;
    int o = (idx >> 8) & 255;
    int c = idx & 255;
    float a0 = attn[b * 4 + 0], a1 = attn[b * 4 + 1],
          a2 = attn[b * 4 + 2], a3 = attn[b * 4 + 3];
    const float* p0 = dyn + ((size_t)o * 256 + c) * 9;
    float v[9];
#pragma unroll
    for (int t = 0; t < 9; ++t)
        v[t] = a0 * p0[t] + a1 * p0[WPERK + t] + a2 * p0[2 * WPERK + t] + a3 * p0[3 * WPERK + t];
    size_t obase = ((size_t)(b * 256 + o) * 9) * 256 + c;
#pragma unroll
    for (int t = 0; t < 9; ++t) {
        float f = v[t];
        unsigned short h = f2bf(f);
        unsigned short l = f2bf(f - bf2f(h));
        wt_hi[obase + (size_t)t * 256] = h;
        wt_lo[obase + (size_t)t * 256] = l;
    }
}

// ---------------- conv via 32x32x16 MFMA ----------------
// 1024 blocks (XCD-swizzled: each XCD owns 2 batches), 256 thr = 4 waves.
// Block tile: 256o x 64px (one output row h). Wave: 64o x 64px, 2x2 frags.
// LDS: 3 input rows x 66 px x 32ch, hi+lo = 31.7KB -> 4-5 blocks/CU.
// FUSED_STATS: epilogue emits per-(block,o) partial sum/sumsq for BN.
template <bool FUSED_STATS>
__global__ __launch_bounds__(256, 2) void conv_mfma_kernel(const float* __restrict__ x,
        const unsigned short* __restrict__ wt_hi,
        const unsigned short* __restrict__ wt_lo,
        float* __restrict__ out,
        float* __restrict__ psum,
        float* __restrict__ psumsq) {
    __shared__ __align__(16) unsigned short xs_hi[3 * 66 * XS_PX];
    __shared__ __align__(16) unsigned short xs_lo[3 * 66 * XS_PX];

    // XCD swizzle: 1024 = 8 XCDs x 128 chunks; chunk -> (b, h)
    const int bid = blockIdx.x;
    const int wk  = (bid & 7) * 128 + (bid >> 3);
    const int b   = wk >> 6;
    const int h   = wk & 63;

    const int tid  = threadIdx.x;
    const int lane = tid & 63;
    const int wid  = tid >> 6;
    const int l31  = lane & 31;
    const int g2   = lane >> 5;
    const int wo   = wid * 64;                 // wave o-base

    // staging role: t -> (r, px), r in 0..2 (input rows h-1..h+1), px in 0..65
    const int sr = tid / 66;
    const int sw = tid - sr * 66;
    const bool sactive = tid < 198;
    const int hh = h - 1 + sr;
    const int ww = sw - 1;
    const bool svalid = sactive && (unsigned)hh < 64u && (unsigned)ww < 64u;
    const float* xsrc = x + (size_t)b * (C_ * HW_) + (size_t)(svalid ? hh : 0) * 64 + (svalid ? ww : 0);
    unsigned short* sh_hi = &xs_hi[(sr * 66 + sw) * XS_PX];
    unsigned short* sh_lo = &xs_lo[(sr * 66 + sw) * XS_PX];

    f32x16 acc[2][2];
#pragma unroll
    for (int i = 0; i < 2; ++i)
#pragma unroll
        for (int j = 0; j < 2; ++j) acc[i][j] = (f32x16)(0.f);

    // per-thread MFMA operand bases
    const unsigned short* wbh = wt_hi + ((size_t)(b * 256 + wo + l31) * 9) * 256 + g2 * 8;
    const unsigned short* wbl = wt_lo + ((size_t)(b * 256 + wo + l31) * 9) * 256 + g2 * 8;
    const unsigned short* xph = xs_hi + l31 * XS_PX + g2 * 8;
    const unsigned short* xpl = xs_lo + l31 * XS_PX + g2 * 8;

#define LOADX(buf, cb) do {                                              \
        if (svalid) {                                                    \
            const float* _p = xsrc + (size_t)(cb) * HW_;                 \
            _Pragma("unroll")                                            \
            for (int _c = 0; _c < 32; ++_c) buf[_c] = _p[(size_t)_c * HW_]; \
        } else {                                                         \
            _Pragma("unroll")                                            \
            for (int _c = 0; _c < 32; ++_c) buf[_c] = 0.f;               \
        }                                                                \
    } while (0)

#define STOREX(buf) do {                                                 \
        if (sactive) {                                                   \
            unsigned _hw[16], _lw[16];                                   \
            _Pragma("unroll")                                            \
            for (int _c = 0; _c < 16; ++_c) {                            \
                unsigned short h0_ = f2bf(buf[2 * _c]);                  \
                unsigned short l0_ = f2bf(buf[2 * _c] - bf2f(h0_));      \
                unsigned short h1_ = f2bf(buf[2 * _c + 1]);              \
                unsigned short l1_ = f2bf(buf[2 * _c + 1] - bf2f(h1_));  \
                _hw[_c] = (unsigned)h0_ | ((unsigned)h1_ << 16);         \
                _lw[_c] = (unsigned)l0_ | ((unsigned)l1_ << 16);         \
            }                                                            \
            _Pragma("unroll")                                            \
            for (int _u = 0; _u < 4; ++_u) {                             \
                *(uint4*)&sh_hi[_u * 8] = make_uint4(_hw[4*_u], _hw[4*_u+1], _hw[4*_u+2], _hw[4*_u+3]); \
                *(uint4*)&sh_lo[_u * 8] = make_uint4(_lw[4*_u], _lw[4*_u+1], _lw[4*_u+2], _lw[4*_u+3]); \
            }                                                            \
        }                                                                \
    } while (0)

#define MFMA_CHUNK(cb) do {                                              \
        _Pragma("unroll")                                                \
        for (int t = 0; t < 9; ++t) {                                    \
            const int dh = t / 3, dw = t % 3;                            \
            bf16x8 bh_[2][2], bl_[2][2];                                 \
            _Pragma("unroll")                                            \
            for (int ks = 0; ks < 2; ++ks)                               \
                _Pragma("unroll")                                        \
                for (int nf = 0; nf < 2; ++nf) {                         \
                    const int xoff = (dh * 66 + dw + nf * 32) * XS_PX + ks * 16; \
                    bh_[ks][nf] = *(const bf16x8*)&xph[xoff];            \
                    bl_[ks][nf] = *(const bf16x8*)&xpl[xoff];            \
                }                                                        \
            bf16x8 ah_[2][2], al_[2][2];                                 \
            _Pragma("unroll")                                            \
            for (int mf = 0; mf < 2; ++mf)                               \
                _Pragma("unroll")                                        \
                for (int ks = 0; ks < 2; ++ks) {                         \
                    const size_t woff = (size_t)mf * 73728 + (size_t)t * 256 + ks * 16 + (cb); \
                    ah_[mf][ks] = *(const bf16x8*)(wbh + woff);          \
                    al_[mf][ks] = *(const bf16x8*)(wbl + woff);          \
                }                                                        \
            __builtin_amdgcn_s_setprio(1);                               \
            _Pragma("unroll")                                            \
            for (int ks = 0; ks < 2; ++ks)                               \
                _Pragma("unroll")                                        \
                for (int mf = 0; mf < 2; ++mf)                           \
                    _Pragma("unroll")                                    \
                    for (int nf = 0; nf < 2; ++nf)                       \
                        acc[mf][nf] = __builtin_amdgcn_mfma_f32_32x32x16_bf16(ah_[mf][ks], bh_[ks][nf], acc[mf][nf], 0, 0, 0); \
            _Pragma("unroll")                                            \
            for (int ks = 0; ks < 2; ++ks)                               \
                _Pragma("unroll")                                        \
                for (int mf = 0; mf < 2; ++mf)                           \
                    _Pragma("unroll")                                    \
                    for (int nf = 0; nf < 2; ++nf)                       \
                        acc[mf][nf] = __builtin_amdgcn_mfma_f32_32x32x16_bf16(ah_[mf][ks], bl_[ks][nf], acc[mf][nf], 0, 0, 0); \
            _Pragma("unroll")                                            \
            for (int ks = 0; ks < 2; ++ks)                               \
                _Pragma("unroll")                                        \
                for (int mf = 0; mf < 2; ++mf)                           \
                    _Pragma("unroll")                                    \
                    for (int nf = 0; nf < 2; ++nf)                       \
                        acc[mf][nf] = __builtin_amdgcn_mfma_f32_32x32x16_bf16(al_[mf][ks], bh_[ks][nf], acc[mf][nf], 0, 0, 0); \
            __builtin_amdgcn_s_setprio(0);                               \
        }                                                                \
    } while (0)

    float xa[32], xb2[32];
    LOADX(xa, 0);
#pragma unroll 1
    for (int cc = 0; cc < 256; cc += 64) {
        __syncthreads();
        STOREX(xa);
        __syncthreads();
        LOADX(xb2, cc + 32);             // T14: issue next-chunk loads before MFMA
        MFMA_CHUNK(cc);
        __syncthreads();
        STOREX(xb2);
        __syncthreads();
        if (cc + 64 < 256) LOADX(xa, cc + 64);
        MFMA_CHUNK(cc + 32);
    }

    // epilogue: C layout (32x32): col=lane&31 (px), row=(r&3)+8*(r>>2)+4*(lane>>5)
    float* op = out + ((size_t)b * 256 + wo) * HW_ + (size_t)h * 64;
#pragma unroll
    for (int mf = 0; mf < 2; ++mf)
#pragma unroll
        for (int nf = 0; nf < 2; ++nf) {
            f32x16 a = acc[mf][nf];
#pragma unroll
            for (int r = 0; r < 16; ++r) {
                int row = (r & 3) + 8 * (r >> 2) + 4 * g2;
                op[(size_t)(mf * 32 + row) * HW_ + nf * 32 + l31] = a[r];
            }
        }

    if (FUSED_STATS) {
        // per-(block,o) partials: sum over 64 px = both nf frags + 32-lane reduce
#pragma unroll
        for (int mf = 0; mf < 2; ++mf)
#pragma unroll
            for (int r = 0; r < 16; ++r) {
                float v0 = acc[mf][0][r], v1 = acc[mf][1][r];
                float s = v0 + v1;
                float q = v0 * v0 + v1 * v1;
#pragma unroll
                for (int off = 1; off < 32; off <<= 1) {
                    s += __shfl_xor(s, off);
                    q += __shfl_xor(q, off);
                }
                if (l31 == 0) {
                    int o = wo + mf * 32 + (r & 3) + 8 * (r >> 2) + 4 * g2;
                    psum[(size_t)o * 1024 + wk] = s;
                    psumsq[(size_t)o * 1024 + wk] = q;
                }
            }
    }
#undef LOADX
#undef STOREX
#undef MFMA_CHUNK
}

// ---------------- fp32 OTF conv fallback (ws too small) ----------------
__global__ __launch_bounds__(256, 2) void conv_otf_kernel(const float* __restrict__ x,
                                                          const float* __restrict__ wsrc,
                                                          const float* __restrict__ attn,
                                                          float* __restrict__ out) {
    __shared__ __align__(16) float xs[8][3][72];
    __shared__ __align__(16) float wsh[64 * 100];
    const int h   = blockIdx.x;
    const int ob  = blockIdx.y * 64;
    const int b   = blockIdx.z;
    const int tid = threadIdx.x;
    const int o_idx = tid >> 4;
    const int w0    = (tid & 15) * 4;
    float a0 = attn[b * 4 + 0], a1 = attn[b * 4 + 1],
          a2 = attn[b * 4 + 2], a3 = attn[b * 4 + 3];
    const float* xb = x + (size_t)b * (C_ * HW_);
    const float* wb = wsrc + (size_t)ob * 2304;
    float acc[4][4];
#pragma unroll
    for (int i = 0; i < 4; ++i)
#pragma unroll
        for (int j = 0; j < 4; ++j) acc[i][j] = 0.f;
    for (int cb = 0; cb < C_; cb += 8) {
        __syncthreads();
        for (int idx = tid; idx < 8 * 3 * 66; idx += 256) {
            int c = idx / 198, rem = idx - c * 198;
            int r = rem / 66, wi = rem - r * 66;
            int hhh = h - 1 + r, ww = wi - 1;
            float v = 0.f;
            if ((unsigned)hhh < 64u && (unsigned)ww < 64u)
                v = xb[(size_t)(cb + c) * HW_ + hhh * 64 + ww];
            xs[c][r][wi] = v;
        }
        for (int idx = tid; idx < 64 * 72; idx += 256) {
            int o = idx / 72, j = idx - o * 72;
            int c = j / 9, t = j - c * 9;
            size_t gi = (size_t)o * 2304 + (size_t)(cb + c) * 9 + t;
            float v = a0 * wb[gi] + a1 * wb[WPERK + gi] +
                      a2 * wb[2 * WPERK + gi] + a3 * wb[3 * WPERK + gi];
            wsh[o * 100 + c * 12 + t] = v;
        }
        __syncthreads();
#pragma unroll
        for (int cc = 0; cc < 8; ++cc) {
            float xr[3][6];
#pragma unroll
            for (int r = 0; r < 3; ++r) {
                float4 a = *(const float4*)&xs[cc][r][w0];
                float2 b2 = *(const float2*)&xs[cc][r][w0 + 4];
                xr[r][0] = a.x; xr[r][1] = a.y; xr[r][2] = a.z; xr[r][3] = a.w;
                xr[r][4] = b2.x; xr[r][5] = b2.y;
            }
#pragma unroll
            for (int oo = 0; oo < 4; ++oo) {
                const float* wp = &wsh[(o_idx * 4 + oo) * 100 + cc * 12];
                float4 wA = *(const float4*)wp;
                float4 wB = *(const float4*)(wp + 4);
                float w8 = wp[8];
#pragma unroll
                for (int ww = 0; ww < 4; ++ww) {
                    acc[oo][ww] += wA.x * xr[0][ww]     + wA.y * xr[0][ww + 1] + wA.z * xr[0][ww + 2]
                                 + wA.w * xr[1][ww]     + wB.x * xr[1][ww + 1] + wB.y * xr[1][ww + 2]
                                 + wB.z * xr[2][ww]     + wB.w * xr[2][ww + 1] + w8   * xr[2][ww + 2];
                }
            }
        }
    }
    float* op = out + ((size_t)b * O_ + ob) * HW_ + h * 64;
#pragma unroll
    for (int oo = 0; oo < 4; ++oo) {
        float4 v = make_float4(acc[oo][0], acc[oo][1], acc[oo][2], acc[oo][3]);
        *(float4*)&op[(size_t)(o_idx * 4 + oo) * HW_ + w0] = v;
    }
}

// ---------------- stats: full fallback (one block per channel) ----------------
__global__ __launch_bounds__(256) void stats_full_kernel(const float4* __restrict__ out4,
                                                         const float* __restrict__ gamma,
                                                         float* __restrict__ mean,
                                                         float* __restrict__ inv) {
    int o = blockIdx.x;
    float s = 0.f, s2 = 0.f;
    for (int b = 0; b < B_; ++b) {
        const float4* p = out4 + ((size_t)b * O_ + o) * PLANE_F4;
        for (int i = threadIdx.x; i < PLANE_F4; i += 256) {
            float4 v = p[i];
            s  += v.x + v.y + v.z + v.w;
            s2 += v.x * v.x + v.y * v.y + v.z * v.z + v.w * v.w;
        }
    }
    for (int off = 32; off; off >>= 1) {
        s  += __shfl_down(s, off);
        s2 += __shfl_down(s2, off);
    }
    __shared__ float ps[4], ps2[4];
    int w = threadIdx.x >> 6;
    if ((threadIdx.x & 63) == 0) { ps[w] = s; ps2[w] = s2; }
    __syncthreads();
    if (threadIdx.x == 0) {
        float S = ps[0] + ps[1] + ps[2] + ps[3];
        float S2 = ps2[0] + ps2[1] + ps2[2] + ps2[3];
        float m = S * (1.f / 65536.f);
        float var = S2 * (1.f / 65536.f) - m * m;
        mean[o] = m;
        inv[o] = gamma[o] * rsqrtf(var + 1e-3f);
    }
}

// ---------------- stats reduce over fused partials: psum[o][1024] ----------------
__global__ __launch_bounds__(256) void stats_reduce_kernel(const float* __restrict__ psum,
                                                           const float* __restrict__ psumsq,
                                                           const float* __restrict__ gamma,
                                                           float* __restrict__ mean,
                                                           float* __restrict__ inv) {
    int o = blockIdx.x;
    const float* ps = psum + (size_t)o * 1024;
    const float* pq = psumsq + (size_t)o * 1024;
    float s = 0.f, q = 0.f;
    for (int i = threadIdx.x; i < 1024; i += 256) { s += ps[i]; q += pq[i]; }
    for (int off = 32; off; off >>= 1) {
        s += __shfl_down(s, off);
        q += __shfl_down(q, off);
    }
    __shared__ float a[4], b2[4];
    int w = threadIdx.x >> 6;
    if ((threadIdx.x & 63) == 0) { a[w] = s; b2[w] = q; }
    __syncthreads();
    if (threadIdx.x == 0) {
        float S = a[0] + a[1] + a[2] + a[3];
        float Q = b2[0] + b2[1] + b2[2] + b2[3];
        float m = S * (1.f / 65536.f);
        float var = Q * (1.f / 65536.f) - m * m;
        mean[o] = m;
        inv[o] = gamma[o] * rsqrtf(var + 1e-3f);
    }
}

// ---------------- BN apply + SiLU ----------------
__global__ __launch_bounds__(256) void bn_silu_kernel(float4* __restrict__ out4,
                                                      const float* __restrict__ mean,
                                                      const float* __restrict__ inv,
                                                      const float* __restrict__ beta) {
    const int total = B_ * O_ * PLANE_F4;
    for (int i = blockIdx.x * 256 + threadIdx.x; i < total; i += gridDim.x * 256) {
        int plane = i >> 10;
        int o = plane & 255;
        float m = mean[o], iv = inv[o], bt = beta[o];
        float4 v = out4[i];
        float u;
        u = (v.x - m) * iv + bt; v.x = u / (1.f + expf(-u));
        u = (v.y - m) * iv + bt; v.y = u / (1.f + expf(-u));
        u = (v.z - m) * iv + bt; v.z = u / (1.f + expf(-u));
        u = (v.w - m) * iv + bt; v.w = u / (1.f + expf(-u));
        out4[i] = v;
    }
}

extern "C" void kernel_launch(void* const* d_in, const int* in_sizes, int n_in,
                              void* d_out, int out_size, void* d_ws, size_t ws_size,
                              hipStream_t stream) {
    const float* x      = (const float*)d_in[0];
    const float* dyn    = (const float*)d_in[1];
    const float* attn_w = (const float*)d_in[2];
    const float* gamma  = (const float*)d_in[3];
    const float* beta   = (const float*)d_in[4];
    float* out = (float*)d_out;
    float* ws  = (float*)d_ws;

    float* pooled = ws;             // 4096
    float* attn   = ws + 4096;      // 64
    float* mean   = ws + 4160;      // 256
    float* inv    = ws + 4416;      // 256
    unsigned short* wt_hi = (unsigned short*)(ws + 4672);   // 9437184 bf16
    unsigned short* wt_lo = wt_hi + 9437184;                // 9437184 bf16
    float* psum   = (float*)(wt_lo + 9437184);              // 262144 f32
    float* psumsq = psum + 262144;                          // 262144 f32

    const size_t need_mfma  = (size_t)4672 * 4 + 2ull * 9437184ull * 2ull;   // 37,767,424
    const size_t need_fused = need_mfma + 2ull * 262144ull * 4ull;           // 39,864,576
    const bool mfma_path = ws_size >= need_mfma;
    const bool fused     = ws_size >= need_fused;

    pool_kernel<<<4096, 256, 0, stream>>>((const float4*)x, pooled);
    attn_kernel<<<1, 64, 0, stream>>>(pooled, attn_w, attn);
    if (mfma_path) {
        wtrans_kernel<<<4096, 256, 0, stream>>>(dyn, attn, wt_hi, wt_lo);
        if (fused) {
            conv_mfma_kernel<true><<<1024, 256, 0, stream>>>(x, wt_hi, wt_lo, out, psum, psumsq);
            stats_reduce_kernel<<<256, 256, 0, stream>>>(psum, psumsq, gamma, mean, inv);
        } else {
            conv_mfma_kernel<false><<<1024, 256, 0, stream>>>(x, wt_hi, wt_lo, out, psum, psumsq);
            stats_full_kernel<<<256, 256, 0, stream>>>((const float4*)out, gamma, mean, inv);
        }
    } else {
        conv_otf_kernel<<<dim3(64, 4, 16), 256, 0, stream>>>(x, dyn, attn, out);
        stats_full_kernel<<<256, 256, 0, stream>>>((const float4*)out, gamma, mean, inv);
    }
    bn_silu_kernel<<<4096, 256, 0, stream>>>((float4*)out, mean, inv, beta);
}

// Round 10
// 415.834 us; speedup vs baseline: 1.1110x; 1.1110x over previous
//
#include <hip/hip_runtime.h>
#include <math.h>

// DynamicConv on MI355X — round 5 (5th resubmit; r5-r9 benches all failed on
// infra — acquisition timeout x4, container failure x1. No data yet.)
// Diagnosis r4: A-operand loads were 32-line gathers (lane stride 4608B) ->
// ~2300 L2 transactions per wave per chunk; waves stalled 70%, MfmaUtil 29%.
// Fix: wt layout [b][t][c16][o][16] -> A-fragment load is 64 lanes x 16B
// fully contiguous. Also: single prefetch buffer (saves 32 VGPR) +
// __launch_bounds__(256,3). Split bf16 hi/lo, 3 MFMA passes; floor ~93us.

#define B_ 16
#define C_ 256
#define O_ 256
#define HW_ 4096          // 64*64
#define PLANE_F4 1024
#define WPERK 589824      // O_*C_*9
#define XS_PX 40          // bf16 slots per pixel in LDS (32 ch + 8 pad)

typedef short bf16x8 __attribute__((ext_vector_type(8)));
typedef float f32x16 __attribute__((ext_vector_type(16)));

__device__ __forceinline__ unsigned short f2bf(float f) {
    unsigned u = __float_as_uint(f);
    u += 0x7FFFu + ((u >> 16) & 1u);
    return (unsigned short)(u >> 16);
}
__device__ __forceinline__ float bf2f(unsigned short h) {
    return __uint_as_float((unsigned)h << 16);
}

// ---------------- pool ----------------
__global__ __launch_bounds__(256) void pool_kernel(const float4* __restrict__ x4,
                                                   float* __restrict__ pooled) {
    int bc = blockIdx.x;
    const float4* p = x4 + (size_t)bc * PLANE_F4;
    float s = 0.f;
    for (int i = threadIdx.x; i < PLANE_F4; i += 256) {
        float4 v = p[i];
        s += v.x + v.y + v.z + v.w;
    }
    for (int off = 32; off; off >>= 1) s += __shfl_down(s, off);
    __shared__ float partial[4];
    if ((threadIdx.x & 63) == 0) partial[threadIdx.x >> 6] = s;
    __syncthreads();
    if (threadIdx.x == 0)
        pooled[bc] = (partial[0] + partial[1] + partial[2] + partial[3]) * (1.f / 4096.f);
}

// ---------------- attn ----------------
__global__ void attn_kernel(const float* __restrict__ pooled,
                            const float* __restrict__ attn_w,
                            float* __restrict__ attn) {
    int tid = threadIdx.x;                     // 64 threads
    int b = tid >> 2, k = tid & 3;
    float s = 0.f;
    for (int c = 0; c < C_; ++c) s += pooled[b * C_ + c] * attn_w[k * C_ + c];
    __shared__ float lg[16][4];
    lg[b][k] = s;
    __syncthreads();
    float m = fmaxf(fmaxf(lg[b][0], lg[b][1]), fmaxf(lg[b][2], lg[b][3]));
    float den = expf(lg[b][0] - m) + expf(lg[b][1] - m) +
                expf(lg[b][2] - m) + expf(lg[b][3] - m);
    attn[tid] = expf(s - m) / den;
}

// ---------------- wtrans: combine, split hi/lo, layout [b][t][c16][o][16] ----------------
// Coalesced A-fragments: lane l31,g2 of frag (t,c16,o-block) reads
// wt[((b*9+t)*16+c16)*4096 + o*16 + g2*8] -> 64 lanes x 16B contiguous.
__global__ __launch_bounds__(256) void wtrans_kernel(const float* __restrict__ dyn,
                                                     const float* __restrict__ attn,
                                                     unsigned short* __restrict__ wt_hi,
                                                     unsigned short* __restrict__ wt_lo) {
    int idx = blockIdx.x * 256 + threadIdx.x;   // (b,o,c)
    int b = idx >> 16;
    int o = (idx >> 8) & 255;
    int c = idx & 255;
    float a0 = attn[b * 4 + 0], a1 = attn[b * 4 + 1],
          a2 = attn[b * 4 + 2], a3 = attn[b * 4 + 3];
    const float* p0 = dyn + ((size_t)o * 256 + c) * 9;
    float v[9];
#pragma unroll
    for (int t = 0; t < 9; ++t)
        v[t] = a0 * p0[t] + a1 * p0[WPERK + t] + a2 * p0[2 * WPERK + t] + a3 * p0[3 * WPERK + t];
#pragma unroll
    for (int t = 0; t < 9; ++t) {
        float f = v[t];
        unsigned short h = f2bf(f);
        unsigned short l = f2bf(f - bf2f(h));
        size_t widx = (((size_t)(b * 9 + t) * 16 + (c >> 4)) * 256 + o) * 16 + (c & 15);
        wt_hi[widx] = h;
        wt_lo[widx] = l;
    }
}

// ---------------- conv via 32x32x16 MFMA ----------------
// 1024 blocks (XCD-swizzled: each XCD owns 2 batches), 256 thr = 4 waves.
// Block tile: 256o x 64px (one output row h). Wave: 64o x 64px, 2x2 frags.
// LDS: 3 input rows x 66 px x 32ch hi+lo = 31.7KB.
template <bool FUSED_STATS>
__global__ __launch_bounds__(256, 3) void conv_mfma_kernel(const float* __restrict__ x,
        const unsigned short* __restrict__ wt_hi,
        const unsigned short* __restrict__ wt_lo,
        float* __restrict__ out,
        float* __restrict__ psum,
        float* __restrict__ psumsq) {
    __shared__ __align__(16) unsigned short xs_hi[3 * 66 * XS_PX];
    __shared__ __align__(16) unsigned short xs_lo[3 * 66 * XS_PX];

    // XCD swizzle: 1024 = 8 XCDs x 128 chunks; chunk -> (b, h)
    const int bid = blockIdx.x;
    const int wk  = (bid & 7) * 128 + (bid >> 3);
    const int b   = wk >> 6;
    const int h   = wk & 63;

    const int tid  = threadIdx.x;
    const int lane = tid & 63;
    const int wid  = tid >> 6;
    const int l31  = lane & 31;
    const int g2   = lane >> 5;
    const int wo   = wid * 64;                 // wave o-base

    // staging role: tid -> (r, px), r in 0..2 (input rows h-1..h+1), px in 0..65
    const int sr = tid / 66;
    const int sw = tid - sr * 66;
    const bool sactive = tid < 198;
    const int hh = h - 1 + sr;
    const int ww = sw - 1;
    const bool svalid = sactive && (unsigned)hh < 64u && (unsigned)ww < 64u;
    const float* xsrc = x + (size_t)b * (C_ * HW_) + (size_t)(svalid ? hh : 0) * 64 + (svalid ? ww : 0);
    unsigned short* sh_hi = &xs_hi[(sr * 66 + sw) * XS_PX];
    unsigned short* sh_lo = &xs_lo[(sr * 66 + sw) * XS_PX];

    f32x16 acc[2][2];
#pragma unroll
    for (int i = 0; i < 2; ++i)
#pragma unroll
        for (int j = 0; j < 2; ++j) acc[i][j] = (f32x16)(0.f);

    // per-thread MFMA operand bases (weights: coalesced layout)
    const unsigned short* wbh = wt_hi + (size_t)b * 589824 + (wo + l31) * 16 + g2 * 8;
    const unsigned short* wbl = wt_lo + (size_t)b * 589824 + (wo + l31) * 16 + g2 * 8;
    const unsigned short* xph = xs_hi + l31 * XS_PX + g2 * 8;
    const unsigned short* xpl = xs_lo + l31 * XS_PX + g2 * 8;

#define LOADX(buf, cb) do {                                              \
        if (svalid) {                                                    \
            const float* _p = xsrc + (size_t)(cb) * HW_;                 \
            _Pragma("unroll")                                            \
            for (int _c = 0; _c < 32; ++_c) buf[_c] = _p[(size_t)_c * HW_]; \
        } else {                                                         \
            _Pragma("unroll")                                            \
            for (int _c = 0; _c < 32; ++_c) buf[_c] = 0.f;               \
        }                                                                \
    } while (0)

#define STOREX(buf) do {                                                 \
        if (sactive) {                                                   \
            _Pragma("unroll")                                            \
            for (int _u = 0; _u < 4; ++_u) {                             \
                unsigned _hw[4], _lw[4];                                 \
                _Pragma("unroll")                                        \
                for (int _c = 0; _c < 4; ++_c) {                         \
                    float _f0 = buf[_u * 8 + 2 * _c];                    \
                    float _f1 = buf[_u * 8 + 2 * _c + 1];                \
                    unsigned short h0_ = f2bf(_f0);                      \
                    unsigned short l0_ = f2bf(_f0 - bf2f(h0_));          \
                    unsigned short h1_ = f2bf(_f1);                      \
                    unsigned short l1_ = f2bf(_f1 - bf2f(h1_));          \
                    _hw[_c] = (unsigned)h0_ | ((unsigned)h1_ << 16);     \
                    _lw[_c] = (unsigned)l0_ | ((unsigned)l1_ << 16);     \
                }                                                        \
                *(uint4*)&sh_hi[_u * 8] = make_uint4(_hw[0], _hw[1], _hw[2], _hw[3]); \
                *(uint4*)&sh_lo[_u * 8] = make_uint4(_lw[0], _lw[1], _lw[2], _lw[3]); \
            }                                                            \
        }                                                                \
    } while (0)

#define MFMA_CHUNK(cb) do {                                              \
        _Pragma("unroll")                                                \
        for (int t = 0; t < 9; ++t) {                                    \
            const int dh = t / 3, dw = t % 3;                            \
            bf16x8 bh_[2][2], bl_[2][2];                                 \
            _Pragma("unroll")                                            \
            for (int ks = 0; ks < 2; ++ks)                               \
                _Pragma("unroll")                                        \
                for (int nf = 0; nf < 2; ++nf) {                         \
                    const int xoff = (dh * 66 + dw + nf * 32) * XS_PX + ks * 16; \
                    bh_[ks][nf] = *(const bf16x8*)&xph[xoff];            \
                    bl_[ks][nf] = *(const bf16x8*)&xpl[xoff];            \
                }                                                        \
            bf16x8 ah_[2][2], al_[2][2];                                 \
            _Pragma("unroll")                                            \
            for (int mf = 0; mf < 2; ++mf)                               \
                _Pragma("unroll")                                        \
                for (int ks = 0; ks < 2; ++ks) {                         \
                    const size_t woff = (size_t)t * 65536 +              \
                        (size_t)(((cb) >> 4) + ks) * 4096 + mf * 512;    \
                    ah_[mf][ks] = *(const bf16x8*)(wbh + woff);          \
                    al_[mf][ks] = *(const bf16x8*)(wbl + woff);          \
                }                                                        \
            __builtin_amdgcn_s_setprio(1);                               \
            _Pragma("unroll")                                            \
            for (int ks = 0; ks < 2; ++ks)                               \
                _Pragma("unroll")                                        \
                for (int mf = 0; mf < 2; ++mf)                           \
                    _Pragma("unroll")                                    \
                    for (int nf = 0; nf < 2; ++nf)                       \
                        acc[mf][nf] = __builtin_amdgcn_mfma_f32_32x32x16_bf16(ah_[mf][ks], bh_[ks][nf], acc[mf][nf], 0, 0, 0); \
            _Pragma("unroll")                                            \
            for (int ks = 0; ks < 2; ++ks)                               \
                _Pragma("unroll")                                        \
                for (int mf = 0; mf < 2; ++mf)                           \
                    _Pragma("unroll")                                    \
                    for (int nf = 0; nf < 2; ++nf)                       \
                        acc[mf][nf] = __builtin_amdgcn_mfma_f32_32x32x16_bf16(ah_[mf][ks], bl_[ks][nf], acc[mf][nf], 0, 0, 0); \
            _Pragma("unroll")                                            \
            for (int ks = 0; ks < 2; ++ks)                               \
                _Pragma("unroll")                                        \
                for (int mf = 0; mf < 2; ++mf)                           \
                    _Pragma("unroll")                                    \
                    for (int nf = 0; nf < 2; ++nf)                       \
                        acc[mf][nf] = __builtin_amdgcn_mfma_f32_32x32x16_bf16(al_[mf][ks], bh_[ks][nf], acc[mf][nf], 0, 0, 0); \
            __builtin_amdgcn_s_setprio(0);                               \
        }                                                                \
    } while (0)

    float xa[32];
    LOADX(xa, 0);
#pragma unroll 1
    for (int cc = 0; cc < 256; cc += 32) {
        __syncthreads();
        STOREX(xa);
        __syncthreads();
        if (cc + 32 < 256) LOADX(xa, cc + 32);   // prefetch in flight under MFMA
        MFMA_CHUNK(cc);
    }

    // epilogue: C layout (32x32): col=lane&31 (px), row=(r&3)+8*(r>>2)+4*(lane>>5)
    float* op = out + ((size_t)b * 256 + wo) * HW_ + (size_t)h * 64;
#pragma unroll
    for (int mf = 0; mf < 2; ++mf)
#pragma unroll
        for (int nf = 0; nf < 2; ++nf) {
            f32x16 a = acc[mf][nf];
#pragma unroll
            for (int r = 0; r < 16; ++r) {
                int row = (r & 3) + 8 * (r >> 2) + 4 * g2;
                op[(size_t)(mf * 32 + row) * HW_ + nf * 32 + l31] = a[r];
            }
        }

    if (FUSED_STATS) {
#pragma unroll
        for (int mf = 0; mf < 2; ++mf)
#pragma unroll
            for (int r = 0; r < 16; ++r) {
                float v0 = acc[mf][0][r], v1 = acc[mf][1][r];
                float s = v0 + v1;
                float q = v0 * v0 + v1 * v1;
#pragma unroll
                for (int off = 1; off < 32; off <<= 1) {
                    s += __shfl_xor(s, off);
                    q += __shfl_xor(q, off);
                }
                if (l31 == 0) {
                    int o = wo + mf * 32 + (r & 3) + 8 * (r >> 2) + 4 * g2;
                    psum[(size_t)o * 1024 + wk] = s;
                    psumsq[(size_t)o * 1024 + wk] = q;
                }
            }
    }
#undef LOADX
#undef STOREX
#undef MFMA_CHUNK
}

// ---------------- fp32 OTF conv fallback (ws too small) ----------------
__global__ __launch_bounds__(256, 2) void conv_otf_kernel(const float* __restrict__ x,
                                                          const float* __restrict__ wsrc,
                                                          const float* __restrict__ attn,
                                                          float* __restrict__ out) {
    __shared__ __align__(16) float xs[8][3][72];
    __shared__ __align__(16) float wsh[64 * 100];
    const int h   = blockIdx.x;
    const int ob  = blockIdx.y * 64;
    const int b   = blockIdx.z;
    const int tid = threadIdx.x;
    const int o_idx = tid >> 4;
    const int w0    = (tid & 15) * 4;
    float a0 = attn[b * 4 + 0], a1 = attn[b * 4 + 1],
          a2 = attn[b * 4 + 2], a3 = attn[b * 4 + 3];
    const float* xb = x + (size_t)b * (C_ * HW_);
    const float* wb = wsrc + (size_t)ob * 2304;
    float acc[4][4];
#pragma unroll
    for (int i = 0; i < 4; ++i)
#pragma unroll
        for (int j = 0; j < 4; ++j) acc[i][j] = 0.f;
    for (int cb = 0; cb < C_; cb += 8) {
        __syncthreads();
        for (int idx = tid; idx < 8 * 3 * 66; idx += 256) {
            int c = idx / 198, rem = idx - c * 198;
            int r = rem / 66, wi = rem - r * 66;
            int hhh = h - 1 + r, ww = wi - 1;
            float v = 0.f;
            if ((unsigned)hhh < 64u && (unsigned)ww < 64u)
                v = xb[(size_t)(cb + c) * HW_ + hhh * 64 + ww];
            xs[c][r][wi] = v;
        }
        for (int idx = tid; idx < 64 * 72; idx += 256) {
            int o = idx / 72, j = idx - o * 72;
            int c = j / 9, t = j - c * 9;
            size_t gi = (size_t)o * 2304 + (size_t)(cb + c) * 9 + t;
            float v = a0 * wb[gi] + a1 * wb[WPERK + gi] +
                      a2 * wb[2 * WPERK + gi] + a3 * wb[3 * WPERK + gi];
            wsh[o * 100 + c * 12 + t] = v;
        }
        __syncthreads();
#pragma unroll
        for (int cc = 0; cc < 8; ++cc) {
            float xr[3][6];
#pragma unroll
            for (int r = 0; r < 3; ++r) {
                float4 a = *(const float4*)&xs[cc][r][w0];
                float2 b2 = *(const float2*)&xs[cc][r][w0 + 4];
                xr[r][0] = a.x; xr[r][1] = a.y; xr[r][2] = a.z; xr[r][3] = a.w;
                xr[r][4] = b2.x; xr[r][5] = b2.y;
            }
#pragma unroll
            for (int oo = 0; oo < 4; ++oo) {
                const float* wp = &wsh[(o_idx * 4 + oo) * 100 + cc * 12];
                float4 wA = *(const float4*)wp;
                float4 wB = *(const float4*)(wp + 4);
                float w8 = wp[8];
#pragma unroll
                for (int ww = 0; ww < 4; ++ww) {
                    acc[oo][ww] += wA.x * xr[0][ww]     + wA.y * xr[0][ww + 1] + wA.z * xr[0][ww + 2]
                                 + wA.w * xr[1][ww]     + wB.x * xr[1][ww + 1] + wB.y * xr[1][ww + 2]
                                 + wB.z * xr[2][ww]     + wB.w * xr[2][ww + 1] + w8   * xr[2][ww + 2];
                }
            }
        }
    }
    float* op = out + ((size_t)b * O_ + ob) * HW_ + h * 64;
#pragma unroll
    for (int oo = 0; oo < 4; ++oo) {
        float4 v = make_float4(acc[oo][0], acc[oo][1], acc[oo][2], acc[oo][3]);
        *(float4*)&op[(size_t)(o_idx * 4 + oo) * HW_ + w0] = v;
    }
}

// ---------------- stats: full fallback (one block per channel) ----------------
__global__ __launch_bounds__(256) void stats_full_kernel(const float4* __restrict__ out4,
                                                         const float* __restrict__ gamma,
                                                         float* __restrict__ mean,
                                                         float* __restrict__ inv) {
    int o = blockIdx.x;
    float s = 0.f, s2 = 0.f;
    for (int b = 0; b < B_; ++b) {
        const float4* p = out4 + ((size_t)b * O_ + o) * PLANE_F4;
        for (int i = threadIdx.x; i < PLANE_F4; i += 256) {
            float4 v = p[i];
            s  += v.x + v.y + v.z + v.w;
            s2 += v.x * v.x + v.y * v.y + v.z * v.z + v.w * v.w;
        }
    }
    for (int off = 32; off; off >>= 1) {
        s  += __shfl_down(s, off);
        s2 += __shfl_down(s2, off);
    }
    __shared__ float ps[4], ps2[4];
    int w = threadIdx.x >> 6;
    if ((threadIdx.x & 63) == 0) { ps[w] = s; ps2[w] = s2; }
    __syncthreads();
    if (threadIdx.x == 0) {
        float S = ps[0] + ps[1] + ps[2] + ps[3];
        float S2 = ps2[0] + ps2[1] + ps2[2] + ps2[3];
        float m = S * (1.f / 65536.f);
        float var = S2 * (1.f / 65536.f) - m * m;
        mean[o] = m;
        inv[o] = gamma[o] * rsqrtf(var + 1e-3f);
    }
}

// ---------------- stats reduce over fused partials: psum[o][1024] ----------------
__global__ __launch_bounds__(256) void stats_reduce_kernel(const float* __restrict__ psum,
                                                           const float* __restrict__ psumsq,
                                                           const float* __restrict__ gamma,
                                                           float* __restrict__ mean,
                                                           float* __restrict__ inv) {
    int o = blockIdx.x;
    const float* ps = psum + (size_t)o * 1024;
    const float* pq = psumsq + (size_t)o * 1024;
    float s = 0.f, q = 0.f;
    for (int i = threadIdx.x; i < 1024; i += 256) { s += ps[i]; q += pq[i]; }
    for (int off = 32; off; off >>= 1) {
        s += __shfl_down(s, off);
        q += __shfl_down(q, off);
    }
    __shared__ float a[4], b2[4];
    int w = threadIdx.x >> 6;
    if ((threadIdx.x & 63) == 0) { a[w] = s; b2[w] = q; }
    __syncthreads();
    if (threadIdx.x == 0) {
        float S = a[0] + a[1] + a[2] + a[3];
        float Q = b2[0] + b2[1] + b2[2] + b2[3];
        float m = S * (1.f / 65536.f);
        float var = Q * (1.f / 65536.f) - m * m;
        mean[o] = m;
        inv[o] = gamma[o] * rsqrtf(var + 1e-3f);
    }
}

// ---------------- BN apply + SiLU ----------------
__global__ __launch_bounds__(256) void bn_silu_kernel(float4* __restrict__ out4,
                                                      const float* __restrict__ mean,
                                                      const float* __restrict__ inv,
                                                      const float* __restrict__ beta) {
    const int total = B_ * O_ * PLANE_F4;
    for (int i = blockIdx.x * 256 + threadIdx.x; i < total; i += gridDim.x * 256) {
        int plane = i >> 10;
        int o = plane & 255;
        float m = mean[o], iv = inv[o], bt = beta[o];
        float4 v = out4[i];
        float u;
        u = (v.x - m) * iv + bt; v.x = u / (1.f + expf(-u));
        u = (v.y - m) * iv + bt; v.y = u / (1.f + expf(-u));
        u = (v.z - m) * iv + bt; v.z = u / (1.f + expf(-u));
        u = (v.w - m) * iv + bt; v.w = u / (1.f + expf(-u));
        out4[i] = v;
    }
}

extern "C" void kernel_launch(void* const* d_in, const int* in_sizes, int n_in,
                              void* d_out, int out_size, void* d_ws, size_t ws_size,
                              hipStream_t stream) {
    const float* x      = (const float*)d_in[0];
    const float* dyn    = (const float*)d_in[1];
    const float* attn_w = (const float*)d_in[2];
    const float* gamma  = (const float*)d_in[3];
    const float* beta   = (const float*)d_in[4];
    float* out = (float*)d_out;
    float* ws  = (float*)d_ws;

    float* pooled = ws;             // 4096
    float* attn   = ws + 4096;      // 64
    float* mean   = ws + 4160;      // 256
    float* inv    = ws + 4416;      // 256
    unsigned short* wt_hi = (unsigned short*)(ws + 4672);   // 9437184 bf16
    unsigned short* wt_lo = wt_hi + 9437184;                // 9437184 bf16
    float* psum   = (float*)(wt_lo + 9437184);              // 262144 f32
    float* psumsq = psum + 262144;                          // 262144 f32

    const size_t need_mfma  = (size_t)4672 * 4 + 2ull * 9437184ull * 2ull;   // 37,767,424
    const size_t need_fused = need_mfma + 2ull * 262144ull * 4ull;           // 39,864,576
    const bool mfma_path = ws_size >= need_mfma;
    const bool fused     = ws_size >= need_fused;

    pool_kernel<<<4096, 256, 0, stream>>>((const float4*)x, pooled);
    attn_kernel<<<1, 64, 0, stream>>>(pooled, attn_w, attn);
    if (mfma_path) {
        wtrans_kernel<<<4096, 256, 0, stream>>>(dyn, attn, wt_hi, wt_lo);
        if (fused) {
            conv_mfma_kernel<true><<<1024, 256, 0, stream>>>(x, wt_hi, wt_lo, out, psum, psumsq);
            stats_reduce_kernel<<<256, 256, 0, stream>>>(psum, psumsq, gamma, mean, inv);
        } else {
            conv_mfma_kernel<false><<<1024, 256, 0, stream>>>(x, wt_hi, wt_lo, out, psum, psumsq);
            stats_full_kernel<<<256, 256, 0, stream>>>((const float4*)out, gamma, mean, inv);
        }
    } else {
        conv_otf_kernel<<<dim3(64, 4, 16), 256, 0, stream>>>(x, dyn, attn, out);
        stats_full_kernel<<<256, 256, 0, stream>>>((const float4*)out, gamma, mean, inv);
    }
    bn_silu_kernel<<<4096, 256, 0, stream>>>((float4*)out, mean, inv, beta);
}